// Round 3
// baseline (381.621 us; speedup 1.0000x reference)
//
#include <hip/hip_runtime.h>
#include <stdint.h>

#define GATE_BIAS 0.6190392084062235f
#define N_TIME 4096
#define NCH 128      /* scan chunks per series */
#define CHL 32       /* timesteps per chunk */

typedef __attribute__((ext_vector_type(4))) short sh4;
typedef __attribute__((ext_vector_type(8))) short sh8;
typedef __attribute__((ext_vector_type(4))) float f32x4;

__device__ __forceinline__ short f2bf(float f) {
  uint32_t u = __float_as_uint(f);
  u = (u + 0x7fffu + ((u >> 16) & 1u)) >> 16;
  return (short)u;
}
__device__ __forceinline__ float bf2f(short s) {
  return __uint_as_float(((uint32_t)(uint16_t)s) << 16);
}

// ---------------------------------------------------------------------------
// GEMM1: raw[m][nn] = sum_k x[m][k]*Wp[nn][k] + b[nn]
// M=16384 N=1024 K=1024. Split-bf16 (hi/lo) 3-product MFMA for ~fp32 accuracy.
// ---------------------------------------------------------------------------
__global__ __launch_bounds__(256) void k_gemm1(const float* __restrict__ x,
                                               const float* __restrict__ Wp,
                                               const float* __restrict__ bp,
                                               float* __restrict__ raw) {
  __shared__ short Ah[128][40], Al[128][40], Bh[128][40], Bl[128][40];
  const int t = threadIdx.x;
  const int row0 = blockIdx.x * 128;
  const int col0 = blockIdx.y * 128;
  const int lane = t & 63;
  const int wave = t >> 6;
  const int wm = wave >> 1, wn = wave & 1;
  const int lrow = lane & 15;
  const int lk = (lane >> 4) * 8;

  f32x4 acc[4][4];
#pragma unroll
  for (int i = 0; i < 4; ++i)
#pragma unroll
    for (int j = 0; j < 4; ++j) acc[i][j] = (f32x4)0.0f;

  for (int k0 = 0; k0 < 1024; k0 += 32) {
    __syncthreads();
#pragma unroll
    for (int i = 0; i < 4; ++i) {
      int f = t + 256 * i;          // 0..1023 float4 slots
      int r = f >> 3, c4 = f & 7;
      float4 va = *(const float4*)(x  + (size_t)(row0 + r) * 1024 + k0 + c4 * 4);
      float4 vb = *(const float4*)(Wp + (size_t)(col0 + r) * 1024 + k0 + c4 * 4);
      sh4 ah, al, bh, bl;
      ah[0] = f2bf(va.x); al[0] = f2bf(va.x - bf2f(ah[0]));
      ah[1] = f2bf(va.y); al[1] = f2bf(va.y - bf2f(ah[1]));
      ah[2] = f2bf(va.z); al[2] = f2bf(va.z - bf2f(ah[2]));
      ah[3] = f2bf(va.w); al[3] = f2bf(va.w - bf2f(ah[3]));
      bh[0] = f2bf(vb.x); bl[0] = f2bf(vb.x - bf2f(bh[0]));
      bh[1] = f2bf(vb.y); bl[1] = f2bf(vb.y - bf2f(bh[1]));
      bh[2] = f2bf(vb.z); bl[2] = f2bf(vb.z - bf2f(bh[2]));
      bh[3] = f2bf(vb.w); bl[3] = f2bf(vb.w - bf2f(bh[3]));
      *(sh4*)&Ah[r][c4 * 4] = ah;
      *(sh4*)&Al[r][c4 * 4] = al;
      *(sh4*)&Bh[r][c4 * 4] = bh;
      *(sh4*)&Bl[r][c4 * 4] = bl;
    }
    __syncthreads();

    sh8 a_h[4], a_l[4], b_h[4], b_l[4];
#pragma unroll
    for (int mi = 0; mi < 4; ++mi) {
      a_h[mi] = *(const sh8*)&Ah[wm * 64 + mi * 16 + lrow][lk];
      a_l[mi] = *(const sh8*)&Al[wm * 64 + mi * 16 + lrow][lk];
      b_h[mi] = *(const sh8*)&Bh[wn * 64 + mi * 16 + lrow][lk];
      b_l[mi] = *(const sh8*)&Bl[wn * 64 + mi * 16 + lrow][lk];
    }
#pragma unroll
    for (int mi = 0; mi < 4; ++mi)
#pragma unroll
      for (int ni = 0; ni < 4; ++ni) {
        acc[mi][ni] = __builtin_amdgcn_mfma_f32_16x16x32_bf16(a_h[mi], b_h[ni], acc[mi][ni], 0, 0, 0);
        acc[mi][ni] = __builtin_amdgcn_mfma_f32_16x16x32_bf16(a_h[mi], b_l[ni], acc[mi][ni], 0, 0, 0);
        acc[mi][ni] = __builtin_amdgcn_mfma_f32_16x16x32_bf16(a_l[mi], b_h[ni], acc[mi][ni], 0, 0, 0);
      }
  }

#pragma unroll
  for (int ni = 0; ni < 4; ++ni) {
    int col = col0 + wn * 64 + ni * 16 + lrow;
    float bias = bp[col];
#pragma unroll
    for (int mi = 0; mi < 4; ++mi)
#pragma unroll
      for (int r = 0; r < 4; ++r) {
        int row = row0 + wm * 64 + mi * 16 + (lane >> 4) * 4 + r;
        raw[(size_t)row * 1024 + col] = acc[mi][ni][r] + bias;
      }
  }
}

// ---------------------------------------------------------------------------
// Activation helper: from raw row -> alpha, drive_r, drive_i, cos, sin
// ---------------------------------------------------------------------------
__device__ __forceinline__ void activ(const float* __restrict__ rowp, int k, int t,
                                      float& alpha, float& dr, float& di,
                                      float& cs, float& sn) {
  float a_raw = rowp[k];
  float w_raw = rowp[256 + k];
  float p_raw = rowp[512 + k];
  float g_raw = rowp[768 + k];
  alpha = 1.0f / (1.0f + expf(-(g_raw + GATE_BIAS)));
  float A = 3.0f / (1.0f + expf(-a_raw));
  float omega = (w_raw > 20.0f) ? w_raw : log1pf(expf(w_raw));
  float pos = log1pf((float)t);
  float angle = fmaf(omega, pos, p_raw);
  sincosf(angle, &sn, &cs);
  float g = (1.0f - alpha) * A;
  dr = g * cs;
  di = g * sn;
}

// pass1: per-chunk totals (A_prod, br, bi)
__global__ __launch_bounds__(256) void k_scan1(const float* __restrict__ raw,
                                               float* __restrict__ totA,
                                               float* __restrict__ totR,
                                               float* __restrict__ totI) {
  const int k = threadIdx.x;
  const int c = blockIdx.x;
  const int b = blockIdx.y;
  const int t0 = c * CHL;
  float Aacc = 1.0f, rr = 0.0f, ri = 0.0f;
  for (int i = 0; i < CHL; ++i) {
    int t = t0 + i;
    const float* rowp = raw + (size_t)(b * N_TIME + t) * 1024;
    float alpha, dr, di, cs, sn;
    activ(rowp, k, t, alpha, dr, di, cs, sn);
    rr = fmaf(alpha, rr, dr);
    ri = fmaf(alpha, ri, di);
    Aacc *= alpha;
  }
  int idx = (b * NCH + c) * 256 + k;
  totA[idx] = Aacc;
  totR[idx] = rr;
  totI[idx] = ri;
}

// pass2: exclusive scan of chunk totals -> carry per chunk
__global__ __launch_bounds__(256) void k_scan2(const float* __restrict__ totA,
                                               const float* __restrict__ totR,
                                               const float* __restrict__ totI,
                                               float* __restrict__ carR,
                                               float* __restrict__ carI) {
  const int k = threadIdx.x;
  const int b = blockIdx.x;
  float rr = 0.0f, ri = 0.0f;
  for (int c = 0; c < NCH; ++c) {
    int idx = (b * NCH + c) * 256 + k;
    carR[idx] = rr;
    carI[idx] = ri;
    float A = totA[idx];
    rr = fmaf(A, rr, totR[idx]);
    ri = fmaf(A, ri, totI[idx]);
  }
}

// pass3: re-scan with carry, normalize, demodulate; rho -> raw[...][k] in place
__global__ __launch_bounds__(256) void k_scan3(float* __restrict__ raw,
                                               const float* __restrict__ carR,
                                               const float* __restrict__ carI) {
  const int k = threadIdx.x;
  const int c = blockIdx.x;
  const int b = blockIdx.y;
  const int t0 = c * CHL;
  int idx = (b * NCH + c) * 256 + k;
  float rr = carR[idx];
  float ri = carI[idx];
  for (int i = 0; i < CHL; ++i) {
    int t = t0 + i;
    float* rowp = raw + (size_t)(b * N_TIME + t) * 1024;
    float alpha, dr, di, cs, sn;
    activ(rowp, k, t, alpha, dr, di, cs, sn);
    rr = fmaf(alpha, rr, dr);
    ri = fmaf(alpha, ri, di);
    float scale = fmaxf(fmaxf(fabsf(rr), fabsf(ri)), 1.0f);
    float rho = (rr * cs + ri * sn) / scale;
    rowp[k] = rho;   // safe: this element already consumed this iteration
  }
}

// ---------------------------------------------------------------------------
// GEMM2: out[m][dd] = rs * sum_k rho[m][k] * Wr[dd][k]
// M=16384 N=1024 K=256. rho lives in raw cols 0..255 (ld=1024). Plain bf16.
// ---------------------------------------------------------------------------
__global__ __launch_bounds__(256) void k_gemm2(const float* __restrict__ rho,
                                               const float* __restrict__ Wr,
                                               const float* __restrict__ rs_ptr,
                                               float* __restrict__ out) {
  __shared__ short Ah[128][40], Bh[128][40];
  const int t = threadIdx.x;
  const int row0 = blockIdx.x * 128;
  const int col0 = blockIdx.y * 128;
  const int lane = t & 63;
  const int wave = t >> 6;
  const int wm = wave >> 1, wn = wave & 1;
  const int lrow = lane & 15;
  const int lk = (lane >> 4) * 8;
  const float rs = *rs_ptr;

  f32x4 acc[4][4];
#pragma unroll
  for (int i = 0; i < 4; ++i)
#pragma unroll
    for (int j = 0; j < 4; ++j) acc[i][j] = (f32x4)0.0f;

  for (int k0 = 0; k0 < 256; k0 += 32) {
    __syncthreads();
#pragma unroll
    for (int i = 0; i < 4; ++i) {
      int f = t + 256 * i;
      int r = f >> 3, c4 = f & 7;
      float4 va = *(const float4*)(rho + (size_t)(row0 + r) * 1024 + k0 + c4 * 4);
      float4 vb = *(const float4*)(Wr  + (size_t)(col0 + r) * 256  + k0 + c4 * 4);
      sh4 ah, bh;
      ah[0] = f2bf(va.x); ah[1] = f2bf(va.y); ah[2] = f2bf(va.z); ah[3] = f2bf(va.w);
      bh[0] = f2bf(vb.x); bh[1] = f2bf(vb.y); bh[2] = f2bf(vb.z); bh[3] = f2bf(vb.w);
      *(sh4*)&Ah[r][c4 * 4] = ah;
      *(sh4*)&Bh[r][c4 * 4] = bh;
    }
    __syncthreads();

    sh8 a_f[4], b_f[4];
#pragma unroll
    for (int mi = 0; mi < 4; ++mi) {
      a_f[mi] = *(const sh8*)&Ah[wm * 64 + mi * 16 + lrow][lk];
      b_f[mi] = *(const sh8*)&Bh[wn * 64 + mi * 16 + lrow][lk];
    }
#pragma unroll
    for (int mi = 0; mi < 4; ++mi)
#pragma unroll
      for (int ni = 0; ni < 4; ++ni)
        acc[mi][ni] = __builtin_amdgcn_mfma_f32_16x16x32_bf16(a_f[mi], b_f[ni], acc[mi][ni], 0, 0, 0);
  }

#pragma unroll
  for (int ni = 0; ni < 4; ++ni) {
    int col = col0 + wn * 64 + ni * 16 + lrow;
#pragma unroll
    for (int mi = 0; mi < 4; ++mi)
#pragma unroll
      for (int r = 0; r < 4; ++r) {
        int row = row0 + wm * 64 + mi * 16 + (lane >> 4) * 4 + r;
        out[(size_t)row * 1024 + col] = rs * acc[mi][ni][r];
      }
  }
}

// ---------------------------------------------------------------------------
extern "C" void kernel_launch(void* const* d_in, const int* in_sizes, int n_in,
                              void* d_out, int out_size, void* d_ws, size_t ws_size,
                              hipStream_t stream) {
  const float* x  = (const float*)d_in[0];
  const float* Wp = (const float*)d_in[1];
  const float* bp = (const float*)d_in[2];
  const float* Wr = (const float*)d_in[3];
  const float* rs = (const float*)d_in[4];
  float* out = (float*)d_out;

  float* raw  = (float*)d_ws;                 // 16384*1024 floats = 64 MB
  float* totA = raw + (size_t)16384 * 1024;   // 4*128*256 each
  float* totR = totA + 4 * NCH * 256;
  float* totI = totR + 4 * NCH * 256;
  float* carR = totI + 4 * NCH * 256;
  float* carI = carR + 4 * NCH * 256;

  k_gemm1<<<dim3(128, 8), 256, 0, stream>>>(x, Wp, bp, raw);
  k_scan1<<<dim3(NCH, 4), 256, 0, stream>>>(raw, totA, totR, totI);
  k_scan2<<<4, 256, 0, stream>>>(totA, totR, totI, carR, carI);
  k_scan3<<<dim3(NCH, 4), 256, 0, stream>>>(raw, carR, carI);
  k_gemm2<<<dim3(128, 8), 256, 0, stream>>>(raw, Wr, rs, out);
}

// Round 6
// 331.005 us; speedup vs baseline: 1.1529x; 1.1529x over previous
//
#include <hip/hip_runtime.h>
#include <stdint.h>

#define GATE_BIAS 0.6190392084062235f
#define N_TIME 4096
#define NCH 128      /* scan chunks per series */
#define CHL 32       /* timesteps per chunk */

typedef __attribute__((ext_vector_type(4))) short sh4;
typedef __attribute__((ext_vector_type(8))) short sh8;
typedef __attribute__((ext_vector_type(4))) float f32x4;

__device__ __forceinline__ short f2bf(float f) {
  uint32_t u = __float_as_uint(f);
  u = (u + 0x7fffu + ((u >> 16) & 1u)) >> 16;
  return (short)u;
}
__device__ __forceinline__ float bf2f(short s) {
  return __uint_as_float(((uint32_t)(uint16_t)s) << 16);
}

// ---------------------------------------------------------------------------
// GEMM1: raw[m][nn] = sum_k x[m][k]*Wp[nn][k] + b[nn]
// M=16384 N=1024 K=1024. Split-bf16 (hi/lo) 3-product MFMA for ~fp32 accuracy.
// (identical to the round-3 kernel that passed at 175us)
// ---------------------------------------------------------------------------
__global__ __launch_bounds__(256) void k_gemm1(const float* __restrict__ x,
                                               const float* __restrict__ Wp,
                                               const float* __restrict__ bp,
                                               float* __restrict__ raw) {
  __shared__ short Ah[128][40], Al[128][40], Bh[128][40], Bl[128][40];
  const int t = threadIdx.x;
  const int row0 = blockIdx.x * 128;
  const int col0 = blockIdx.y * 128;
  const int lane = t & 63;
  const int wave = t >> 6;
  const int wm = wave >> 1, wn = wave & 1;
  const int lrow = lane & 15;
  const int lk = (lane >> 4) * 8;

  f32x4 acc[4][4];
#pragma unroll
  for (int i = 0; i < 4; ++i)
#pragma unroll
    for (int j = 0; j < 4; ++j) acc[i][j] = (f32x4)0.0f;

  for (int k0 = 0; k0 < 1024; k0 += 32) {
    __syncthreads();
#pragma unroll
    for (int i = 0; i < 4; ++i) {
      int f = t + 256 * i;          // 0..1023 float4 slots
      int r = f >> 3, c4 = f & 7;
      float4 va = *(const float4*)(x  + (size_t)(row0 + r) * 1024 + k0 + c4 * 4);
      float4 vb = *(const float4*)(Wp + (size_t)(col0 + r) * 1024 + k0 + c4 * 4);
      sh4 ah, al, bh, bl;
      ah[0] = f2bf(va.x); al[0] = f2bf(va.x - bf2f(ah[0]));
      ah[1] = f2bf(va.y); al[1] = f2bf(va.y - bf2f(ah[1]));
      ah[2] = f2bf(va.z); al[2] = f2bf(va.z - bf2f(ah[2]));
      ah[3] = f2bf(va.w); al[3] = f2bf(va.w - bf2f(ah[3]));
      bh[0] = f2bf(vb.x); bl[0] = f2bf(vb.x - bf2f(bh[0]));
      bh[1] = f2bf(vb.y); bl[1] = f2bf(vb.y - bf2f(bh[1]));
      bh[2] = f2bf(vb.z); bl[2] = f2bf(vb.z - bf2f(bh[2]));
      bh[3] = f2bf(vb.w); bl[3] = f2bf(vb.w - bf2f(bh[3]));
      *(sh4*)&Ah[r][c4 * 4] = ah;
      *(sh4*)&Al[r][c4 * 4] = al;
      *(sh4*)&Bh[r][c4 * 4] = bh;
      *(sh4*)&Bl[r][c4 * 4] = bl;
    }
    __syncthreads();

    sh8 a_h[4], a_l[4], b_h[4], b_l[4];
#pragma unroll
    for (int mi = 0; mi < 4; ++mi) {
      a_h[mi] = *(const sh8*)&Ah[wm * 64 + mi * 16 + lrow][lk];
      a_l[mi] = *(const sh8*)&Al[wm * 64 + mi * 16 + lrow][lk];
      b_h[mi] = *(const sh8*)&Bh[wn * 64 + mi * 16 + lrow][lk];
      b_l[mi] = *(const sh8*)&Bl[wn * 64 + mi * 16 + lrow][lk];
    }
#pragma unroll
    for (int mi = 0; mi < 4; ++mi)
#pragma unroll
      for (int ni = 0; ni < 4; ++ni) {
        acc[mi][ni] = __builtin_amdgcn_mfma_f32_16x16x32_bf16(a_h[mi], b_h[ni], acc[mi][ni], 0, 0, 0);
        acc[mi][ni] = __builtin_amdgcn_mfma_f32_16x16x32_bf16(a_h[mi], b_l[ni], acc[mi][ni], 0, 0, 0);
        acc[mi][ni] = __builtin_amdgcn_mfma_f32_16x16x32_bf16(a_l[mi], b_h[ni], acc[mi][ni], 0, 0, 0);
      }
  }

#pragma unroll
  for (int ni = 0; ni < 4; ++ni) {
    int col = col0 + wn * 64 + ni * 16 + lrow;
    float bias = bp[col];
#pragma unroll
    for (int mi = 0; mi < 4; ++mi)
#pragma unroll
      for (int r = 0; r < 4; ++r) {
        int row = row0 + wm * 64 + mi * 16 + (lane >> 4) * 4 + r;
        raw[(size_t)row * 1024 + col] = acc[mi][ni][r] + bias;
      }
  }
}

// ---------------------------------------------------------------------------
// Activation helper (native-math): raw row -> alpha, drive, cos, sin
// ---------------------------------------------------------------------------
__device__ __forceinline__ void activ(const float* __restrict__ rowp, int k, float pos,
                                      float& alpha, float& dr, float& di,
                                      float& cs, float& sn) {
  float a_raw = rowp[k];
  float w_raw = rowp[256 + k];
  float p_raw = rowp[512 + k];
  float g_raw = rowp[768 + k];
  alpha = 1.0f / (1.0f + __expf(-(g_raw + GATE_BIAS)));
  float A = 3.0f / (1.0f + __expf(-a_raw));
  float omega = (w_raw > 15.0f) ? w_raw : __logf(1.0f + __expf(w_raw));
  float angle = fmaf(omega, pos, p_raw);
  __sincosf(angle, &sn, &cs);
  float g = (1.0f - alpha) * A;
  dr = g * cs;
  di = g * sn;
}

// pass1: per-chunk totals (A_prod, br, bi)
__global__ __launch_bounds__(256) void k_scan1(const float* __restrict__ raw,
                                               float* __restrict__ totA,
                                               float* __restrict__ totR,
                                               float* __restrict__ totI) {
  const int k = threadIdx.x;
  const int c = blockIdx.x;
  const int b = blockIdx.y;
  const int t0 = c * CHL;
  float Aacc = 1.0f, rr = 0.0f, ri = 0.0f;
  for (int i = 0; i < CHL; ++i) {
    int t = t0 + i;
    const float* rowp = raw + (size_t)(b * N_TIME + t) * 1024;
    float pos = __logf((float)(t + 1));
    float alpha, dr, di, cs, sn;
    activ(rowp, k, pos, alpha, dr, di, cs, sn);
    rr = fmaf(alpha, rr, dr);
    ri = fmaf(alpha, ri, di);
    Aacc *= alpha;
  }
  int idx = (b * NCH + c) * 256 + k;
  totA[idx] = Aacc;
  totR[idx] = rr;
  totI[idx] = ri;
}

// pass2: exclusive scan of chunk totals -> carry per chunk
__global__ __launch_bounds__(256) void k_scan2(const float* __restrict__ totA,
                                               const float* __restrict__ totR,
                                               const float* __restrict__ totI,
                                               float* __restrict__ carR,
                                               float* __restrict__ carI) {
  const int k = threadIdx.x;
  const int b = blockIdx.x;
  float rr = 0.0f, ri = 0.0f;
  for (int c = 0; c < NCH; ++c) {
    int idx = (b * NCH + c) * 256 + k;
    carR[idx] = rr;
    carI[idx] = ri;
    float A = totA[idx];
    rr = fmaf(A, rr, totR[idx]);
    ri = fmaf(A, ri, totI[idx]);
  }
}

// pass3: re-scan with carry, normalize, demodulate; rho -> raw[...][k] in place
__global__ __launch_bounds__(256) void k_scan3(float* __restrict__ raw,
                                               const float* __restrict__ carR,
                                               const float* __restrict__ carI) {
  const int k = threadIdx.x;
  const int c = blockIdx.x;
  const int b = blockIdx.y;
  const int t0 = c * CHL;
  int idx = (b * NCH + c) * 256 + k;
  float rr = carR[idx];
  float ri = carI[idx];
  for (int i = 0; i < CHL; ++i) {
    int t = t0 + i;
    float* rowp = raw + (size_t)(b * N_TIME + t) * 1024;
    float pos = __logf((float)(t + 1));
    float alpha, dr, di, cs, sn;
    activ(rowp, k, pos, alpha, dr, di, cs, sn);
    rr = fmaf(alpha, rr, dr);
    ri = fmaf(alpha, ri, di);
    float scale = fmaxf(fmaxf(fabsf(rr), fabsf(ri)), 1.0f);
    float rho = (rr * cs + ri * sn) / scale;
    rowp[k] = rho;   // safe: this element already consumed this iteration
  }
}

// ---------------------------------------------------------------------------
// GEMM2: out[m][dd] = rs * sum_k rho[m][k] * Wr[dd][k]
// M=16384 N=1024 K=256. rho lives in raw cols 0..255 (ld=1024). Plain bf16.
// ---------------------------------------------------------------------------
__global__ __launch_bounds__(256) void k_gemm2(const float* __restrict__ rho,
                                               const float* __restrict__ Wr,
                                               const float* __restrict__ rs_ptr,
                                               float* __restrict__ out) {
  __shared__ short Ah[128][40], Bh[128][40];
  const int t = threadIdx.x;
  const int row0 = blockIdx.x * 128;
  const int col0 = blockIdx.y * 128;
  const int lane = t & 63;
  const int wave = t >> 6;
  const int wm = wave >> 1, wn = wave & 1;
  const int lrow = lane & 15;
  const int lk = (lane >> 4) * 8;
  const float rs = *rs_ptr;

  f32x4 acc[4][4];
#pragma unroll
  for (int i = 0; i < 4; ++i)
#pragma unroll
    for (int j = 0; j < 4; ++j) acc[i][j] = (f32x4)0.0f;

  for (int k0 = 0; k0 < 256; k0 += 32) {
    __syncthreads();
#pragma unroll
    for (int i = 0; i < 4; ++i) {
      int f = t + 256 * i;
      int r = f >> 3, c4 = f & 7;
      float4 va = *(const float4*)(rho + (size_t)(row0 + r) * 1024 + k0 + c4 * 4);
      float4 vb = *(const float4*)(Wr  + (size_t)(col0 + r) * 256  + k0 + c4 * 4);
      sh4 ah, bh;
      ah[0] = f2bf(va.x); ah[1] = f2bf(va.y); ah[2] = f2bf(va.z); ah[3] = f2bf(va.w);
      bh[0] = f2bf(vb.x); bh[1] = f2bf(vb.y); bh[2] = f2bf(vb.z); bh[3] = f2bf(vb.w);
      *(sh4*)&Ah[r][c4 * 4] = ah;
      *(sh4*)&Bh[r][c4 * 4] = bh;
    }
    __syncthreads();

    sh8 a_f[4], b_f[4];
#pragma unroll
    for (int mi = 0; mi < 4; ++mi) {
      a_f[mi] = *(const sh8*)&Ah[wm * 64 + mi * 16 + lrow][lk];
      b_f[mi] = *(const sh8*)&Bh[wn * 64 + mi * 16 + lrow][lk];
    }
#pragma unroll
    for (int mi = 0; mi < 4; ++mi)
#pragma unroll
      for (int ni = 0; ni < 4; ++ni)
        acc[mi][ni] = __builtin_amdgcn_mfma_f32_16x16x32_bf16(a_f[mi], b_f[ni], acc[mi][ni], 0, 0, 0);
  }

#pragma unroll
  for (int ni = 0; ni < 4; ++ni) {
    int col = col0 + wn * 64 + ni * 16 + lrow;
#pragma unroll
    for (int mi = 0; mi < 4; ++mi)
#pragma unroll
      for (int r = 0; r < 4; ++r) {
        int row = row0 + wm * 64 + mi * 16 + (lane >> 4) * 4 + r;
        out[(size_t)row * 1024 + col] = rs * acc[mi][ni][r];
      }
  }
}

// ---------------------------------------------------------------------------
extern "C" void kernel_launch(void* const* d_in, const int* in_sizes, int n_in,
                              void* d_out, int out_size, void* d_ws, size_t ws_size,
                              hipStream_t stream) {
  const float* x  = (const float*)d_in[0];
  const float* Wp = (const float*)d_in[1];
  const float* bp = (const float*)d_in[2];
  const float* Wr = (const float*)d_in[3];
  const float* rs = (const float*)d_in[4];
  float* out = (float*)d_out;

  float* raw  = (float*)d_ws;                 // 16384*1024 floats = 64 MB
  float* totA = raw + (size_t)16384 * 1024;   // 4*128*256 each
  float* totR = totA + 4 * NCH * 256;
  float* totI = totR + 4 * NCH * 256;
  float* carR = totI + 4 * NCH * 256;
  float* carI = carR + 4 * NCH * 256;

  k_gemm1<<<dim3(128, 8), 256, 0, stream>>>(x, Wp, bp, raw);
  k_scan1<<<dim3(NCH, 4), 256, 0, stream>>>(raw, totA, totR, totI);
  k_scan2<<<4, 256, 0, stream>>>(totA, totR, totI, carR, carI);
  k_scan3<<<dim3(NCH, 4), 256, 0, stream>>>(raw, carR, carI);
  k_gemm2<<<dim3(128, 8), 256, 0, stream>>>(raw, Wr, rs, out);
}

// Round 9
// 298.742 us; speedup vs baseline: 1.2774x; 1.1080x over previous
//
#include <hip/hip_runtime.h>
#include <stdint.h>

#define GATE_BIAS 0.6190392084062235f
#define N_TIME 4096
#define NCH 128      /* scan chunks per series */
#define CHL 32       /* timesteps per chunk */

typedef __attribute__((ext_vector_type(4))) short sh4;
typedef __attribute__((ext_vector_type(8))) short sh8;
typedef __attribute__((ext_vector_type(4))) float f32x4;

__device__ __forceinline__ short f2bf(float f) {
  uint32_t u = __float_as_uint(f);
  u = (u + 0x7fffu + ((u >> 16) & 1u)) >> 16;
  return (short)u;
}
__device__ __forceinline__ float bf2f(short s) {
  return __uint_as_float(((uint32_t)(uint16_t)s) << 16);
}

// ---------------------------------------------------------------------------
// Pre-split: f32 -> bf16 hi/lo planes.  n4 = number of FLOAT4 chunks.
// ---------------------------------------------------------------------------
__global__ __launch_bounds__(256) void k_split(const float* __restrict__ src,
                                               short* __restrict__ dh,
                                               short* __restrict__ dl, int n4) {
  int i = blockIdx.x * 256 + threadIdx.x;
  int stride = gridDim.x * 256;
  for (; i < n4; i += stride) {
    float4 v = *(const float4*)(src + (size_t)i * 4);
    sh4 h, l;
    h[0] = f2bf(v.x); l[0] = f2bf(v.x - bf2f(h[0]));
    h[1] = f2bf(v.y); l[1] = f2bf(v.y - bf2f(h[1]));
    h[2] = f2bf(v.z); l[2] = f2bf(v.z - bf2f(h[2]));
    h[3] = f2bf(v.w); l[3] = f2bf(v.w - bf2f(h[3]));
    *(sh4*)(dh + (size_t)i * 4) = h;
    *(sh4*)(dl + (size_t)i * 4) = l;
  }
}
__global__ __launch_bounds__(256) void k_cvt(const float* __restrict__ src,
                                             short* __restrict__ dst, int n4) {
  int i = blockIdx.x * 256 + threadIdx.x;
  int stride = gridDim.x * 256;
  for (; i < n4; i += stride) {
    float4 v = *(const float4*)(src + (size_t)i * 4);
    sh4 h;
    h[0] = f2bf(v.x); h[1] = f2bf(v.y); h[2] = f2bf(v.z); h[3] = f2bf(v.w);
    *(sh4*)(dst + (size_t)i * 4) = h;
  }
}

// ---------------------------------------------------------------------------
// GEMM1: raw[m][nn] = sum_k x[m][k]*Wp[nn][k] + b[nn]
// M=16384 N=1024 K=1024. Split-bf16 3-product MFMA.
// A (x): f32 loads + in-kernel split.  B (Wp): pre-split bf16 plane loads.
// ---------------------------------------------------------------------------
__global__ __launch_bounds__(256) void k_gemm1(const float* __restrict__ x,
                                               const short* __restrict__ wph,
                                               const short* __restrict__ wpl,
                                               const float* __restrict__ bp,
                                               float* __restrict__ raw) {
  __shared__ short Ah[128][40], Al[128][40], Bh[128][40], Bl[128][40];
  const int t = threadIdx.x;
  const int row0 = blockIdx.x * 128;
  const int col0 = blockIdx.y * 128;
  const int lane = t & 63;
  const int wave = t >> 6;
  const int wm = wave >> 1, wn = wave & 1;
  const int lrow = lane & 15;
  const int lk = (lane >> 4) * 8;

  f32x4 acc[4][4];
#pragma unroll
  for (int i = 0; i < 4; ++i)
#pragma unroll
    for (int j = 0; j < 4; ++j) acc[i][j] = (f32x4)0.0f;

  for (int k0 = 0; k0 < 1024; k0 += 32) {
    __syncthreads();
    // ---- A staging: f32 -> hi/lo split ----
#pragma unroll
    for (int i = 0; i < 4; ++i) {
      int f = t + 256 * i;          // 1024 float4 slots
      int r = f >> 3, c4 = f & 7;
      float4 va = *(const float4*)(x + (size_t)(row0 + r) * 1024 + k0 + c4 * 4);
      sh4 ah, al;
      ah[0] = f2bf(va.x); al[0] = f2bf(va.x - bf2f(ah[0]));
      ah[1] = f2bf(va.y); al[1] = f2bf(va.y - bf2f(ah[1]));
      ah[2] = f2bf(va.z); al[2] = f2bf(va.z - bf2f(ah[2]));
      ah[3] = f2bf(va.w); al[3] = f2bf(va.w - bf2f(ah[3]));
      *(sh4*)&Ah[r][c4 * 4] = ah;
      *(sh4*)&Al[r][c4 * 4] = al;
    }
    // ---- B staging: pure vector loads from pre-split planes ----
#pragma unroll
    for (int i = 0; i < 2; ++i) {
      int f = t + 256 * i;          // 512 short8 slots = 128 rows x 4
      int r = f >> 2, c8 = f & 3;
      size_t g = (size_t)(col0 + r) * 1024 + k0 + c8 * 8;
      *(sh8*)&Bh[r][c8 * 8] = *(const sh8*)(wph + g);
      *(sh8*)&Bl[r][c8 * 8] = *(const sh8*)(wpl + g);
    }
    __syncthreads();

    sh8 a_h[4], a_l[4], b_h[4], b_l[4];
#pragma unroll
    for (int mi = 0; mi < 4; ++mi) {
      a_h[mi] = *(const sh8*)&Ah[wm * 64 + mi * 16 + lrow][lk];
      a_l[mi] = *(const sh8*)&Al[wm * 64 + mi * 16 + lrow][lk];
      b_h[mi] = *(const sh8*)&Bh[wn * 64 + mi * 16 + lrow][lk];
      b_l[mi] = *(const sh8*)&Bl[wn * 64 + mi * 16 + lrow][lk];
    }
#pragma unroll
    for (int mi = 0; mi < 4; ++mi)
#pragma unroll
      for (int ni = 0; ni < 4; ++ni) {
        acc[mi][ni] = __builtin_amdgcn_mfma_f32_16x16x32_bf16(a_h[mi], b_h[ni], acc[mi][ni], 0, 0, 0);
        acc[mi][ni] = __builtin_amdgcn_mfma_f32_16x16x32_bf16(a_h[mi], b_l[ni], acc[mi][ni], 0, 0, 0);
        acc[mi][ni] = __builtin_amdgcn_mfma_f32_16x16x32_bf16(a_l[mi], b_h[ni], acc[mi][ni], 0, 0, 0);
      }
  }

#pragma unroll
  for (int ni = 0; ni < 4; ++ni) {
    int col = col0 + wn * 64 + ni * 16 + lrow;
    float bias = bp[col];
#pragma unroll
    for (int mi = 0; mi < 4; ++mi)
#pragma unroll
      for (int r = 0; r < 4; ++r) {
        int row = row0 + wm * 64 + mi * 16 + (lane >> 4) * 4 + r;
        raw[(size_t)row * 1024 + col] = acc[mi][ni][r] + bias;
      }
  }
}

// ---------------------------------------------------------------------------
// Activation helper (native-math): raw row -> alpha, drive, cos, sin
// ---------------------------------------------------------------------------
__device__ __forceinline__ void activ(const float* __restrict__ rowp, int k, float pos,
                                      float& alpha, float& dr, float& di,
                                      float& cs, float& sn) {
  float a_raw = rowp[k];
  float w_raw = rowp[256 + k];
  float p_raw = rowp[512 + k];
  float g_raw = rowp[768 + k];
  alpha = 1.0f / (1.0f + __expf(-(g_raw + GATE_BIAS)));
  float A = 3.0f / (1.0f + __expf(-a_raw));
  float omega = (w_raw > 15.0f) ? w_raw : __logf(1.0f + __expf(w_raw));
  float angle = fmaf(omega, pos, p_raw);
  __sincosf(angle, &sn, &cs);
  float g = (1.0f - alpha) * A;
  dr = g * cs;
  di = g * sn;
}

// pass1: per-chunk totals (A_prod, br, bi)
__global__ __launch_bounds__(256) void k_scan1(const float* __restrict__ raw,
                                               float* __restrict__ totA,
                                               float* __restrict__ totR,
                                               float* __restrict__ totI) {
  const int k = threadIdx.x;
  const int c = blockIdx.x;
  const int b = blockIdx.y;
  const int t0 = c * CHL;
  float Aacc = 1.0f, rr = 0.0f, ri = 0.0f;
  for (int i = 0; i < CHL; ++i) {
    int t = t0 + i;
    const float* rowp = raw + (size_t)(b * N_TIME + t) * 1024;
    float pos = __logf((float)(t + 1));
    float alpha, dr, di, cs, sn;
    activ(rowp, k, pos, alpha, dr, di, cs, sn);
    rr = fmaf(alpha, rr, dr);
    ri = fmaf(alpha, ri, di);
    Aacc *= alpha;
  }
  int idx = (b * NCH + c) * 256 + k;
  totA[idx] = Aacc;
  totR[idx] = rr;
  totI[idx] = ri;
}

// pass2: exclusive scan of chunk totals -> carry per chunk
__global__ __launch_bounds__(256) void k_scan2(const float* __restrict__ totA,
                                               const float* __restrict__ totR,
                                               const float* __restrict__ totI,
                                               float* __restrict__ carR,
                                               float* __restrict__ carI) {
  const int k = threadIdx.x;
  const int b = blockIdx.x;
  float rr = 0.0f, ri = 0.0f;
#pragma unroll 8
  for (int c = 0; c < NCH; ++c) {
    int idx = (b * NCH + c) * 256 + k;
    carR[idx] = rr;
    carI[idx] = ri;
    float A = totA[idx];
    rr = fmaf(A, rr, totR[idx]);
    ri = fmaf(A, ri, totI[idx]);
  }
}

// pass3: re-scan with carry, normalize, demodulate; write bf16 rho (ld=256)
__global__ __launch_bounds__(256) void k_scan3(const float* __restrict__ raw,
                                               const float* __restrict__ carR,
                                               const float* __restrict__ carI,
                                               short* __restrict__ rho_b) {
  const int k = threadIdx.x;
  const int c = blockIdx.x;
  const int b = blockIdx.y;
  const int t0 = c * CHL;
  int idx = (b * NCH + c) * 256 + k;
  float rr = carR[idx];
  float ri = carI[idx];
  for (int i = 0; i < CHL; ++i) {
    int t = t0 + i;
    const float* rowp = raw + (size_t)(b * N_TIME + t) * 1024;
    float pos = __logf((float)(t + 1));
    float alpha, dr, di, cs, sn;
    activ(rowp, k, pos, alpha, dr, di, cs, sn);
    rr = fmaf(alpha, rr, dr);
    ri = fmaf(alpha, ri, di);
    float scale = fmaxf(fmaxf(fabsf(rr), fabsf(ri)), 1.0f);
    float rho = (rr * cs + ri * sn) / scale;
    rho_b[(size_t)(b * N_TIME + t) * 256 + k] = f2bf(rho);
  }
}

// ---------------------------------------------------------------------------
// GEMM2: out[m][dd] = rs * sum_k rho[m][k] * Wr[dd][k]
// M=16384 N=1024 K=256. Pure bf16 inputs: rho_b (ld 256), wrb (ld 256).
// ---------------------------------------------------------------------------
__global__ __launch_bounds__(256) void k_gemm2(const short* __restrict__ rho_b,
                                               const short* __restrict__ wrb,
                                               const float* __restrict__ rs_ptr,
                                               float* __restrict__ out) {
  __shared__ short Ah[128][40], Bh[128][40];
  const int t = threadIdx.x;
  const int row0 = blockIdx.x * 128;
  const int col0 = blockIdx.y * 128;
  const int lane = t & 63;
  const int wave = t >> 6;
  const int wm = wave >> 1, wn = wave & 1;
  const int lrow = lane & 15;
  const int lk = (lane >> 4) * 8;
  const float rs = *rs_ptr;

  f32x4 acc[4][4];
#pragma unroll
  for (int i = 0; i < 4; ++i)
#pragma unroll
    for (int j = 0; j < 4; ++j) acc[i][j] = (f32x4)0.0f;

  for (int k0 = 0; k0 < 256; k0 += 32) {
    __syncthreads();
#pragma unroll
    for (int i = 0; i < 2; ++i) {
      int f = t + 256 * i;
      int r = f >> 2, c8 = f & 3;
      *(sh8*)&Ah[r][c8 * 8] = *(const sh8*)(rho_b + (size_t)(row0 + r) * 256 + k0 + c8 * 8);
      *(sh8*)&Bh[r][c8 * 8] = *(const sh8*)(wrb  + (size_t)(col0 + r) * 256 + k0 + c8 * 8);
    }
    __syncthreads();

    sh8 a_f[4], b_f[4];
#pragma unroll
    for (int mi = 0; mi < 4; ++mi) {
      a_f[mi] = *(const sh8*)&Ah[wm * 64 + mi * 16 + lrow][lk];
      b_f[mi] = *(const sh8*)&Bh[wn * 64 + mi * 16 + lrow][lk];
    }
#pragma unroll
    for (int mi = 0; mi < 4; ++mi)
#pragma unroll
      for (int ni = 0; ni < 4; ++ni)
        acc[mi][ni] = __builtin_amdgcn_mfma_f32_16x16x32_bf16(a_f[mi], b_f[ni], acc[mi][ni], 0, 0, 0);
  }

#pragma unroll
  for (int ni = 0; ni < 4; ++ni) {
    int col = col0 + wn * 64 + ni * 16 + lrow;
#pragma unroll
    for (int mi = 0; mi < 4; ++mi)
#pragma unroll
      for (int r = 0; r < 4; ++r) {
        int row = row0 + wm * 64 + mi * 16 + (lane >> 4) * 4 + r;
        out[(size_t)row * 1024 + col] = rs * acc[mi][ni][r];
      }
  }
}

// ---------------------------------------------------------------------------
extern "C" void kernel_launch(void* const* d_in, const int* in_sizes, int n_in,
                              void* d_out, int out_size, void* d_ws, size_t ws_size,
                              hipStream_t stream) {
  const float* x  = (const float*)d_in[0];
  const float* Wp = (const float*)d_in[1];
  const float* bp = (const float*)d_in[2];
  const float* Wr = (const float*)d_in[3];
  const float* rs = (const float*)d_in[4];
  float* out = (float*)d_out;

  char* base = (char*)d_ws;
  // layout (bytes), total 82,837,504 < proven ws floor of 95,420,416:
  //   raw     [0, 67108864)             64 MB f32 (16384 x 1024)
  //   tot/car [67108864, 69730304)      5 x 524288 f32 arrays
  //   wph     [69730304, 71827456)      2 MB bf16 (1024 x 1024)
  //   wpl     [71827456, 73924608)      2 MB bf16
  //   wrb     [73924608, 74448896)      0.5 MB bf16 (1024 x 256)
  //   rho_b   [74448896, 82837504)      8 MB bf16 (16384 x 256)
  float* raw   = (float*)base;
  float* totA  = (float*)(base + 67108864);
  float* totR  = totA + 131072;
  float* totI  = totR + 131072;
  float* carR  = totI + 131072;
  float* carI  = carR + 131072;
  short* wph   = (short*)(base + 69730304);
  short* wpl   = (short*)(base + 71827456);
  short* wrb   = (short*)(base + 73924608);
  short* rho_b = (short*)(base + 74448896);

  // Wp: 1024x1024 floats = 262144 float4 chunks.  Wr: 1024x256 = 65536 chunks.
  k_split<<<1024, 256, 0, stream>>>(Wp, wph, wpl, 262144);
  k_cvt  <<<256,  256, 0, stream>>>(Wr, wrb, 65536);

  k_gemm1<<<dim3(128, 8), 256, 0, stream>>>(x, wph, wpl, bp, raw);
  k_scan1<<<dim3(NCH, 4), 256, 0, stream>>>(raw, totA, totR, totI);
  k_scan2<<<4, 256, 0, stream>>>(totA, totR, totI, carR, carI);
  k_scan3<<<dim3(NCH, 4), 256, 0, stream>>>(raw, carR, carI, rho_b);
  k_gemm2<<<dim3(128, 8), 256, 0, stream>>>(rho_b, wrb, rs, out);
}